// Round 1
// baseline (1094.320 us; speedup 1.0000x reference)
//
#include <hip/hip_runtime.h>
#include <hip/hip_cooperative_groups.h>

namespace cg = cooperative_groups;

#define NN 1000
#define NE 64000
#define HH 256

typedef _Float16 half8 __attribute__((ext_vector_type(8)));
typedef float floatx4 __attribute__((ext_vector_type(4)));

struct PrepArgs { const float* w0[5]; const float* w1[5]; };

struct MegaArgs {
    const float* x;
    const int* ei;
    const float* w0[5];
    const float* b0[5];
    const float* w1[5];
    const float* b1[5];
    int* ssrc; int* sdst; int* counts; int* cursor;
    _Float16* node_ab;
    float* aggA; float* aggB;
    _Float16* wnode; _Float16* w2h;
    float* out;
};

// ---------------------------------------------------------------------------
// Shared device helpers (same numerics as the verified 13-kernel version).
// node_tile: C = X[M,Kd] @ Wn^T, 16x128 tile (252 tiles); Wn pre-swizzled into
// MFMA B-fragment order. Per-kk load+MFMA keeps VGPR pressure under the
// launch_bounds(256,4) cap of 128.
// ---------------------------------------------------------------------------
template <int NK>
__device__ __forceinline__ void node_tile(const float* __restrict__ X,
                                          const _Float16* __restrict__ Wn,
                                          const float* __restrict__ b0,
                                          _Float16* __restrict__ out, int bid) {
    const int Kd = NK * 32;
    int t = threadIdx.x;
    int wave = t >> 6, lane = t & 63;
    int q = lane >> 4, mn = lane & 15;
    int m0 = (bid % 63) * 16;
    int n0 = (bid / 63) * 128 + wave * 32;
    int slice = (bid / 63) * 4 + wave;
    int rr = m0 + mn;
    if (rr >= NN) rr = NN - 1;
    floatx4 acc[2] = {};
#pragma unroll
    for (int kk = 0; kk < NK; kk++) {
        int ka = kk * 32 + q * 8;
        const float* p = X + (size_t)rr * Kd + ka;
        floatx4 x0 = *(const floatx4*)p;
        floatx4 x1 = *(const floatx4*)(p + 4);
        half8 aa;
#pragma unroll
        for (int j = 0; j < 4; j++) { aa[j] = (_Float16)x0[j]; aa[4 + j] = (_Float16)x1[j]; }
        half8 bf0 = *(const half8*)(Wn + (((slice * NK + kk) * 2 + 0) * 64 + lane) * 8);
        half8 bf1 = *(const half8*)(Wn + (((slice * NK + kk) * 2 + 1) * 64 + lane) * 8);
        acc[0] = __builtin_amdgcn_mfma_f32_16x16x32_f16(aa, bf0, acc[0], 0, 0, 0);
        acc[1] = __builtin_amdgcn_mfma_f32_16x16x32_f16(aa, bf1, acc[1], 0, 0, 0);
    }
#pragma unroll
    for (int nt = 0; nt < 2; nt++) {
        int col = n0 + nt * 16 + mn;
        float bias = (col < 256) ? b0[col] : 0.f;
#pragma unroll
        for (int r2 = 0; r2 < 4; r2++) {
            int orow = m0 + q * 4 + r2;
            if (orow < NN)
                out[(size_t)orow * 512 + col] = (_Float16)(acc[nt][r2] + bias);
        }
    }
}

// 64 sorted edges x 256 cols. h1 = relu(a[dst]+b[src]) in XOR-swizzled LDS;
// W2 in fragment order -> coalesced b128 loads; epilogue merges same-dst runs
// then atomicMax(uint) into zero-initialized agg (values clamped >= 0).
__device__ __forceinline__ void edge_tile(const _Float16* __restrict__ node_ab,
                                          const int* __restrict__ ssrc,
                                          const int* __restrict__ sdst,
                                          const _Float16* __restrict__ W2,
                                          const float* __restrict__ b2,
                                          float* __restrict__ agg, int tile,
                                          _Float16* h1, int* sd) {
    int t = threadIdx.x;
    int e0 = tile * 64;
    int wave = t >> 6, lane = t & 63;
    int q = lane >> 4, mn = lane & 15;
    int n0 = wave * 64;
    const _Float16* W2w = W2 + wave * 16384;

    __syncthreads();  // protect h1/sd reuse across consecutive tiles
    if (t < 64) sd[t] = sdst[e0 + t];
    {   // staging: all 16 gather loads in flight
        int row = t & 63;
        int cb = (t >> 6) * 8;
        int dn = sdst[e0 + row], sn = ssrc[e0 + row];
        const _Float16* pa = node_ab + (size_t)dn * 512 + cb * 8;
        const _Float16* pb = node_ab + (size_t)sn * 512 + 256 + cb * 8;
        half8 av[8], bv[8];
#pragma unroll
        for (int i = 0; i < 8; i++) av[i] = *(const half8*)(pa + i * 8);
#pragma unroll
        for (int i = 0; i < 8; i++) bv[i] = *(const half8*)(pb + i * 8);
#pragma unroll
        for (int i = 0; i < 8; i++) {
            int c = cb + i;
            int p = (c & ~7) | ((c ^ row) & 7);
            half8 hv = av[i] + bv[i];
#pragma unroll
            for (int j = 0; j < 8; j++) hv[j] = hv[j] > (_Float16)0 ? hv[j] : (_Float16)0;
            *(half8*)(&h1[row * 256 + p * 8]) = hv;
        }
    }
    __syncthreads();

    floatx4 acc[4][4] = {};
#pragma unroll
    for (int kk = 0; kk < 8; kk++) {
        half8 bf[4];
#pragma unroll
        for (int nt = 0; nt < 4; nt++)
            bf[nt] = *(const half8*)(W2w + (kk * 4 + nt) * 512 + lane * 8);  // coalesced
        half8 af[4];
#pragma unroll
        for (int mt = 0; mt < 4; mt++) {
            int r = mt * 16 + mn;
            int c = kk * 4 + q;
            int p = (c & ~7) | ((c ^ r) & 7);
            af[mt] = *(const half8*)(&h1[r * 256 + p * 8]);
        }
#pragma unroll
        for (int mt = 0; mt < 4; mt++)
#pragma unroll
            for (int nt = 0; nt < 4; nt++)
                acc[mt][nt] = __builtin_amdgcn_mfma_f32_16x16x32_f16(af[mt], bf[nt], acc[mt][nt], 0, 0, 0);
    }

#pragma unroll
    for (int nt = 0; nt < 4; nt++) {
        int col = n0 + nt * 16 + mn;
        float bias = b2[col];
        int curd = -1;
        float curv = 0.f;
#pragma unroll
        for (int mt = 0; mt < 4; mt++) {
#pragma unroll
            for (int r2 = 0; r2 < 4; r2++) {
                int er = mt * 16 + q * 4 + r2;  // monotone -> sorted runs merge
                int d = sd[er];
                float v = acc[mt][nt][r2] + bias;
                v = v > 0.f ? v : 0.f;
                if (d != curd) {
                    if (curd >= 0 && curv > 0.f)
                        atomicMax((unsigned int*)(agg + (size_t)curd * HH + col), __float_as_uint(curv));
                    curd = d;
                    curv = v;
                } else {
                    curv = fmaxf(curv, v);
                }
            }
        }
        if (curd >= 0 && curv > 0.f)
            atomicMax((unsigned int*)(agg + (size_t)curd * HH + col), __float_as_uint(curv));
    }
}

// ---------------------------------------------------------------------------
// THE fused persistent kernel. One dispatch replaces the 13-kernel pipeline;
// 12 grid.sync()s replace 12 kernel boundaries (drain + gap + re-ramp each).
// Scan (block 0) overlaps the 252 layer-0 node-GEMM tiles. All phases are
// grid-strided so any co-resident grid size >= 256 is correct.
// LDS = 32 KB h1 + sd + scan = ~34 KB -> 4 blocks/CU; VGPR capped at 128 by
// launch_bounds(256,4) -> 1024-block co-residency; grid = min(1000, occ*256).
// ---------------------------------------------------------------------------
__global__ __launch_bounds__(256, 4) void mega(MegaArgs A) {
    __shared__ _Float16 h1[64 * 256];
    __shared__ int sd[64];
    __shared__ int sscan[256];
    cg::grid_group grid = cg::this_grid();
    const int nb = gridDim.x;
    const int bid = blockIdx.x;
    const int t = threadIdx.x;
    const int gtid = bid * 256 + t;
    const int gs = nb * 256;

    // ---- P0a: zero hist counters, swizzle all weights to fp16 fragment order,
    //           zero aggA
    for (int i = gtid; i < 1024; i += gs) A.counts[i] = 0;
    for (int l = 0; l < 5; l++) {
        const int KK = l ? 8 : 4;
        const int D = KK * 32;
        const int lgKK = l ? 3 : 2;
        const float* w0 = A.w0[l];
        _Float16* wn = A.wnode + l * 131072;
        for (int i = gtid; i < 16384 * KK; i += gs) {
            int j = i & 7;
            int lane = (i >> 3) & 63;
            int nt = (i >> 9) & 1;
            int kk = (i >> 10) & (KK - 1);
            int slice = i >> (10 + lgKK);
            int mn = lane & 15, q = lane >> 4;
            int n = slice * 32 + nt * 16 + mn;
            int k = kk * 32 + q * 8 + j;
            float v = (n < 256) ? (w0[n * 2 * D + k] - w0[n * 2 * D + D + k])
                                : w0[(n - 256) * 2 * D + D + k];
            wn[i] = (_Float16)v;
        }
        const float* w1 = A.w1[l];
        _Float16* w2 = A.w2h + l * 65536;
        for (int i = gtid; i < 65536; i += gs) {
            int j = i & 7;
            int lane = (i >> 3) & 63;
            int nt = (i >> 9) & 3;
            int kk = (i >> 11) & 7;
            int ws = (i >> 14) & 3;
            int mn = lane & 15, q = lane >> 4;
            int row = ws * 64 + nt * 16 + mn;
            int col = kk * 32 + q * 8 + j;
            w2[i] = (_Float16)w1[row * 256 + col];
        }
    }
    {
        floatx4 z = {0.f, 0.f, 0.f, 0.f};
        floatx4* p4 = (floatx4*)A.aggA;
        for (int i = gtid; i < NN * HH / 4; i += gs) p4[i] = z;
    }
    grid.sync();

    // ---- P0b: dst histogram (needs zeroed counters)
    for (int e = gtid; e < NE; e += gs) atomicAdd(&A.counts[A.ei[NE + e] & 1023], 1);
    grid.sync();

    // ---- P1: block 0 exclusive-scans counts->cursor; blocks 1.. do layer-0
    //          node GEMM (252 tiles) concurrently
    if (bid == 0) {
        int base = t * 4;
        int c4[4]; int sum = 0;
#pragma unroll
        for (int j = 0; j < 4; j++) { c4[j] = A.counts[base + j]; sum += c4[j]; }
        sscan[t] = sum;
        __syncthreads();
        for (int d = 1; d < 256; d <<= 1) {
            int v = (t >= d) ? sscan[t - d] : 0;
            __syncthreads();
            sscan[t] += v;
            __syncthreads();
        }
        int run = (t > 0) ? sscan[t - 1] : 0;
#pragma unroll
        for (int j = 0; j < 4; j++) { A.cursor[base + j] = run; run += c4[j]; }
    } else {
        for (int tile = bid - 1; tile < 252; tile += nb - 1)
            node_tile<4>(A.x, A.wnode, A.b0[0], A.node_ab, tile);
    }
    grid.sync();

    // ---- P2: counting-sort scatter of edges by dst
    for (int e = gtid; e < NE; e += gs) {
        int s = A.ei[e] & 1023, d = A.ei[NE + e] & 1023;
        int pos = atomicAdd(&A.cursor[d], 1);
        if (pos < NE) { A.ssrc[pos] = s; A.sdst[pos] = d; }
    }
    grid.sync();

    // ---- 5 layers: edge GEMM + scatter-max, then (l<4) node GEMM + zero next agg
#pragma unroll 1
    for (int l = 0; l < 5; l++) {
        const _Float16* W2 = A.w2h + l * 65536;
        const float* b2 = A.b1[l];
        float* agg = (l == 4) ? A.out : ((l & 1) ? A.aggB : A.aggA);
        for (int tile = bid; tile < NE / 64; tile += nb)
            edge_tile(A.node_ab, A.ssrc, A.sdst, W2, b2, agg, tile, h1, sd);
        if (l < 4) {
            grid.sync();
            float* aggn = (l == 3) ? A.out : ((l & 1) ? A.aggA : A.aggB);
            for (int tile = bid; tile < 252; tile += nb)
                node_tile<8>(agg, A.wnode + (size_t)(l + 1) * 131072, A.b0[l + 1],
                             A.node_ab, tile);
            floatx4 z = {0.f, 0.f, 0.f, 0.f};
            floatx4* p4 = (floatx4*)aggn;
            for (int i = gtid; i < NN * HH / 4; i += gs) p4[i] = z;
            grid.sync();
        }
    }
}

// ---------------------------------------------------------------------------
// Fallback: the verified 13-kernel pipeline (used only if cooperative launch
// is unavailable). Same device helpers -> same numerics.
// ---------------------------------------------------------------------------
__global__ __launch_bounds__(256) void k_prep(PrepArgs pa,
                                              _Float16* wnode, _Float16* w2h,
                                              int* counts, float* aggA) {
    int gtid = blockIdx.x * 256 + threadIdx.x;
    int gstride = gridDim.x * 256;
    for (int i = gtid; i < 1024; i += gstride) counts[i] = 0;
    for (int l = 0; l < 5; l++) {
        const int KK = l ? 8 : 4;
        const int D = KK * 32;
        const int lgKK = l ? 3 : 2;
        const float* w0 = pa.w0[l];
        _Float16* wn = wnode + l * 131072;
        for (int i = gtid; i < 16384 * KK; i += gstride) {
            int j = i & 7;
            int lane = (i >> 3) & 63;
            int nt = (i >> 9) & 1;
            int kk = (i >> 10) & (KK - 1);
            int slice = i >> (10 + lgKK);
            int mn = lane & 15, q = lane >> 4;
            int n = slice * 32 + nt * 16 + mn;
            int k = kk * 32 + q * 8 + j;
            float v = (n < 256) ? (w0[n * 2 * D + k] - w0[n * 2 * D + D + k])
                                : w0[(n - 256) * 2 * D + D + k];
            wn[i] = (_Float16)v;
        }
        const float* w1 = pa.w1[l];
        _Float16* w2 = w2h + l * 65536;
        for (int i = gtid; i < 65536; i += gstride) {
            int j = i & 7;
            int lane = (i >> 3) & 63;
            int nt = (i >> 9) & 3;
            int kk = (i >> 11) & 7;
            int ws = (i >> 14) & 3;
            int mn = lane & 15, q = lane >> 4;
            int row = ws * 64 + nt * 16 + mn;
            int col = kk * 32 + q * 8 + j;
            w2[i] = (_Float16)w1[row * 256 + col];
        }
    }
    floatx4 z = {0.f, 0.f, 0.f, 0.f};
    floatx4* p4 = (floatx4*)aggA;
    for (int i = gtid; i < NN * HH / 4; i += gstride) p4[i] = z;
}

__global__ __launch_bounds__(256) void k_hist_node0(const int* __restrict__ ei,
                                                    int* __restrict__ counts,
                                                    const float* __restrict__ X,
                                                    const _Float16* __restrict__ Wn,
                                                    const float* __restrict__ b0,
                                                    _Float16* __restrict__ out) {
    int bid = blockIdx.x;
    if (bid < 4) {
        for (int e = bid * 256 + threadIdx.x; e < NE; e += 4 * 256)
            atomicAdd(&counts[ei[NE + e] & 1023], 1);
    } else {
        node_tile<4>(X, Wn, b0, out, bid - 4);
    }
}

__global__ __launch_bounds__(256) void k_scan(const int* __restrict__ counts,
                                              int* __restrict__ cursor) {
    __shared__ int s[256];
    int t = threadIdx.x;
    int base = t * 4;
    int c4[4]; int sum = 0;
#pragma unroll
    for (int j = 0; j < 4; j++) { c4[j] = counts[base + j]; sum += c4[j]; }
    s[t] = sum;
    __syncthreads();
    for (int d = 1; d < 256; d <<= 1) {
        int v = (t >= d) ? s[t - d] : 0;
        __syncthreads();
        s[t] += v;
        __syncthreads();
    }
    int run = (t > 0) ? s[t - 1] : 0;
#pragma unroll
    for (int j = 0; j < 4; j++) { cursor[base + j] = run; run += c4[j]; }
}

__global__ __launch_bounds__(256) void k_scatter(const int* __restrict__ ei,
                                                 int* __restrict__ cursor,
                                                 int* __restrict__ ssrc, int* __restrict__ sdst) {
    int e = blockIdx.x * blockDim.x + threadIdx.x;
    if (e < NE) {
        int s = ei[e] & 1023, d = ei[NE + e] & 1023;
        int pos = atomicAdd(&cursor[d], 1);
        if (pos < NE) {
            ssrc[pos] = s;
            sdst[pos] = d;
        }
    }
}

__global__ __launch_bounds__(256) void k_node_zero(const float* __restrict__ agg_in,
                                                   const _Float16* __restrict__ Wn,
                                                   const float* __restrict__ b0,
                                                   _Float16* __restrict__ out,
                                                   float* __restrict__ agg_next) {
    int bid = blockIdx.x;
    if (bid < 252) {
        node_tile<8>(agg_in, Wn, b0, out, bid);
    } else {
        floatx4 z = {0.f, 0.f, 0.f, 0.f};
        floatx4* p4 = (floatx4*)agg_next;
        for (int i = (bid - 252) * 256 + (int)threadIdx.x; i < NN * HH / 4; i += 64 * 256)
            p4[i] = z;
    }
}

__global__ __launch_bounds__(256, 4) void edge_gemm(const _Float16* __restrict__ node_ab,
                          const int* __restrict__ ssrc, const int* __restrict__ sdst,
                          const _Float16* __restrict__ W2, const float* __restrict__ b2,
                          float* __restrict__ agg) {
    __shared__ _Float16 h1[64 * 256];
    __shared__ int sd[64];
    edge_tile(node_ab, ssrc, sdst, W2, b2, agg, blockIdx.x, h1, sd);
}

extern "C" void kernel_launch(void* const* d_in, const int* in_sizes, int n_in,
                              void* d_out, int out_size, void* d_ws, size_t ws_size,
                              hipStream_t stream) {
    const float* x = (const float*)d_in[0];
    const int* ei = (const int*)d_in[1];  // int32 per harness contract

    int* ssrc = (int*)d_ws;                              // 256 KB
    int* sdst = ssrc + NE;                               // 256 KB
    int* counts = sdst + NE;                             // 4 KB
    int* cursor = counts + 1024;                         // 4 KB
    _Float16* node_ab = (_Float16*)(cursor + 1024);      // [1024][512] fp16, 1 MB
    float* aggA = (float*)(node_ab + 1024 * 512);        // 1 MB
    float* aggB = aggA + NN * HH;                        // 1 MB
    _Float16* wnode = (_Float16*)(aggB + NN * HH);       // 5 x 131072 halfs
    _Float16* w2h = wnode + 5 * 131072;                  // 5 x 65536 halfs

    MegaArgs A;
    A.x = x; A.ei = ei;
    for (int l = 0; l < 5; l++) {
        A.w0[l] = (const float*)d_in[2 + 4 * l];
        A.b0[l] = (const float*)d_in[3 + 4 * l];
        A.w1[l] = (const float*)d_in[4 + 4 * l];
        A.b1[l] = (const float*)d_in[5 + 4 * l];
    }
    A.ssrc = ssrc; A.sdst = sdst; A.counts = counts; A.cursor = cursor;
    A.node_ab = node_ab; A.aggA = aggA; A.aggB = aggB;
    A.wnode = wnode; A.w2h = w2h;
    A.out = (float*)d_out;

    // Grid sized to guaranteed co-residency (cooperative requirement).
    static int coopGrid = -1;
    if (coopGrid < 0) {
        int maxb = 0;
        if (hipOccupancyMaxActiveBlocksPerMultiprocessor(&maxb, (const void*)mega, 256, 0)
                != hipSuccess)
            maxb = 0;
        int cap = maxb * 256;  // 256 CUs on MI355X
        coopGrid = (cap >= 256) ? (cap > 1000 ? 1000 : cap) : 0;
    }

    bool done = false;
    if (coopGrid > 0) {
        void* kargs[1] = { (void*)&A };
        hipError_t e = hipLaunchCooperativeKernel((const void*)mega, dim3(coopGrid),
                                                  dim3(256), kargs, 0, stream);
        if (e == hipSuccess) {
            done = true;
        } else {
            (void)hipGetLastError();  // clear sticky error before fallback
        }
    }

    if (!done) {
        PrepArgs pa;
        const float* b0s[5]; const float* b1s[5];
        for (int l = 0; l < 5; l++) {
            pa.w0[l] = A.w0[l]; b0s[l] = A.b0[l];
            pa.w1[l] = A.w1[l]; b1s[l] = A.b1[l];
        }
        hipLaunchKernelGGL(k_prep, dim3(256), dim3(256), 0, stream, pa, wnode, w2h, counts, aggA);
        hipLaunchKernelGGL(k_hist_node0, dim3(256), dim3(256), 0, stream, ei, counts, x, wnode, b0s[0], node_ab);
        hipLaunchKernelGGL(k_scan, dim3(1), dim3(256), 0, stream, counts, cursor);
        hipLaunchKernelGGL(k_scatter, dim3((NE + 255) / 256), dim3(256), 0, stream, ei, cursor, ssrc, sdst);
        float* aggs[5] = {aggA, aggB, aggA, aggB, (float*)d_out};
        for (int l = 0; l < 5; l++) {
            hipLaunchKernelGGL(edge_gemm, dim3(NE / 64), dim3(256), 0, stream,
                               node_ab, ssrc, sdst, w2h + (size_t)l * 65536, b1s[l], aggs[l]);
            if (l < 4)
                hipLaunchKernelGGL(k_node_zero, dim3(252 + 64), dim3(256), 0, stream,
                                   aggs[l], wnode + (size_t)(l + 1) * 131072, b0s[l + 1],
                                   node_ab, aggs[l + 1]);
        }
    }
}

// Round 2
// 538.174 us; speedup vs baseline: 2.0334x; 2.0334x over previous
//
#include <hip/hip_runtime.h>

#define NN 1000
#define NE 64000
#define HH 256

typedef _Float16 half8 __attribute__((ext_vector_type(8)));
typedef float floatx4 __attribute__((ext_vector_type(4)));

struct PrepArgs { const float* w0[5]; const float* w1[5]; };

// ---------------------------------------------------------------------------
// Pipeline (8 dispatches, no grid.sync — cooperative sync measured at
// ~110 µs/sync on 8 XCDs due to L2 writeback+invalidate; kernel boundaries
// are cheaper):
//   1. k_prep2      : zero counts/cursor; swizzle weights (wnode0 frag order,
//                     W2 frag order x5, WpT transposed-plain x4)
//   2. k_hist_node0 : dst histogram (4 blocks) + layer-0 node GEMM (252 blocks)
//   3. k_scatter2   : per-block replicated prefix scan of counts (kills the
//                     single-block k_scan dispatch) + counting-sort scatter
//   4-8. fused_layer: ONE BLOCK PER DST NODE — edge MLP chunks of 64 in LDS,
//                     MFMA, masked max-reduce in regs + shfl (no atomics, no
//                     agg buffers), then the NEXT layer's node row as a
//                     coalesced GEMV (WpT), or final relu->out for layer 4.
// node_ab double-buffered (F reads other dsts' rows while writing its own).
// ---------------------------------------------------------------------------

__global__ __launch_bounds__(256) void k_prep2(PrepArgs pa,
                                               _Float16* wnode0, _Float16* w2h,
                                               _Float16* wpT,
                                               int* counts, int* cursor) {
    int gtid = blockIdx.x * 256 + threadIdx.x;
    int gs = gridDim.x * 256;
    for (int i = gtid; i < 1024; i += gs) { counts[i] = 0; cursor[i] = 0; }

    // layer-0 node weights -> MFMA B-fragment order (for node_tile<4>)
    {
        const float* w0 = pa.w0[0];
        for (int i = gtid; i < 65536; i += gs) {
            int j = i & 7;
            int lane = (i >> 3) & 63;
            int nt = (i >> 9) & 1;
            int kk = (i >> 10) & 3;
            int slice = i >> 12;
            int mn = lane & 15, q = lane >> 4;
            int n = slice * 32 + nt * 16 + mn;
            int k = kk * 32 + q * 8 + j;
            // layer0: D=128, w0 row stride 256; A = Wa-Wb, B = Wb
            float v = (n < 256) ? (w0[n * 256 + k] - w0[n * 256 + 128 + k])
                                : w0[(n - 256) * 256 + 128 + k];
            wnode0[i] = (_Float16)v;
        }
    }
    // W2 (edge MLP layer 2) -> fragment order, all 5 layers
    for (int l = 0; l < 5; l++) {
        const float* w1 = pa.w1[l];
        _Float16* w2 = w2h + l * 65536;
        for (int i = gtid; i < 65536; i += gs) {
            int j = i & 7;
            int lane = (i >> 3) & 63;
            int nt = (i >> 9) & 3;
            int kk = (i >> 11) & 7;
            int ws = (i >> 14) & 3;
            int mn = lane & 15, q = lane >> 4;
            int row = ws * 64 + nt * 16 + mn;
            int col = kk * 32 + q * 8 + j;
            w2[i] = (_Float16)w1[row * 256 + col];
        }
    }
    // layers 1..4 node weights -> transposed plain fp16 WpT[k][n] (GEMV-coalesced)
    // n<256: (Wa-Wb)[n][k] ; n>=256: Wb[n-256][k]   (w0 is [256][512], D=256)
    for (int i = gtid; i < 4 * 131072; i += gs) {
        int l = (i >> 17) + 1;
        int r = i & 131071;
        int k = r >> 9;     // 0..255
        int n = r & 511;    // 0..511
        const float* w0 = pa.w0[l];
        float v = (n < 256) ? (w0[n * 512 + k] - w0[n * 512 + 256 + k])
                            : w0[(n - 256) * 512 + 256 + k];
        wpT[i] = (_Float16)v;   // i == (l-1)*131072 + k*512 + n  -> coalesced write
    }
}

// C = X[M,Kd] @ Wn^T, 16x128 tile per block (252 tiles); Wn in fragment order.
template <int NK>
__device__ __forceinline__ void node_tile(const float* __restrict__ X,
                                          const _Float16* __restrict__ Wn,
                                          const float* __restrict__ b0,
                                          _Float16* __restrict__ out, int bid) {
    const int Kd = NK * 32;
    int t = threadIdx.x;
    int wave = t >> 6, lane = t & 63;
    int q = lane >> 4, mn = lane & 15;
    int m0 = (bid % 63) * 16;
    int n0 = (bid / 63) * 128 + wave * 32;
    int slice = (bid / 63) * 4 + wave;
    int rr = m0 + mn;
    if (rr >= NN) rr = NN - 1;
    floatx4 acc[2] = {};
#pragma unroll
    for (int kk = 0; kk < NK; kk++) {
        int ka = kk * 32 + q * 8;
        const float* p = X + (size_t)rr * Kd + ka;
        floatx4 x0 = *(const floatx4*)p;
        floatx4 x1 = *(const floatx4*)(p + 4);
        half8 aa;
#pragma unroll
        for (int j = 0; j < 4; j++) { aa[j] = (_Float16)x0[j]; aa[4 + j] = (_Float16)x1[j]; }
        half8 bf0 = *(const half8*)(Wn + (((slice * NK + kk) * 2 + 0) * 64 + lane) * 8);
        half8 bf1 = *(const half8*)(Wn + (((slice * NK + kk) * 2 + 1) * 64 + lane) * 8);
        acc[0] = __builtin_amdgcn_mfma_f32_16x16x32_f16(aa, bf0, acc[0], 0, 0, 0);
        acc[1] = __builtin_amdgcn_mfma_f32_16x16x32_f16(aa, bf1, acc[1], 0, 0, 0);
    }
#pragma unroll
    for (int nt = 0; nt < 2; nt++) {
        int col = n0 + nt * 16 + mn;
        float bias = (col < 256) ? b0[col] : 0.f;
#pragma unroll
        for (int r2 = 0; r2 < 4; r2++) {
            int orow = m0 + q * 4 + r2;
            if (orow < NN)
                out[(size_t)orow * 512 + col] = (_Float16)(acc[nt][r2] + bias);
        }
    }
}

// blocks 0..3: dst histogram; blocks 4..255: layer-0 node GEMM
__global__ __launch_bounds__(256) void k_hist_node0(const int* __restrict__ ei,
                                                    int* __restrict__ counts,
                                                    const float* __restrict__ X,
                                                    const _Float16* __restrict__ Wn,
                                                    const float* __restrict__ b0,
                                                    _Float16* __restrict__ out) {
    int bid = blockIdx.x;
    if (bid < 4) {
        for (int e = bid * 256 + threadIdx.x; e < NE; e += 4 * 256)
            atomicAdd(&counts[ei[NE + e] & 1023], 1);
    } else {
        node_tile<4>(X, Wn, b0, out, bid - 4);
    }
}

// Each block re-runs the 1024-entry exclusive scan locally (~1 µs, concurrent)
// -> no single-block scan dispatch. Block 0 also publishes rowptr for F-layers.
__global__ __launch_bounds__(256) void k_scatter2(const int* __restrict__ ei,
                                                  const int* __restrict__ counts,
                                                  int* __restrict__ cursor,
                                                  int* __restrict__ rowptr,
                                                  int* __restrict__ ssrc) {
    __shared__ int sbase[1024];
    __shared__ int ssum[256];
    int t = threadIdx.x;
    int base = t * 4;
    int c4[4]; int sum = 0;
#pragma unroll
    for (int j = 0; j < 4; j++) { c4[j] = counts[base + j]; sum += c4[j]; }
    ssum[t] = sum;
    __syncthreads();
    for (int d = 1; d < 256; d <<= 1) {
        int v = (t >= d) ? ssum[t - d] : 0;
        __syncthreads();
        ssum[t] += v;
        __syncthreads();
    }
    int run = (t > 0) ? ssum[t - 1] : 0;
#pragma unroll
    for (int j = 0; j < 4; j++) { sbase[base + j] = run; run += c4[j]; }
    __syncthreads();
    if (blockIdx.x == 0) {
#pragma unroll
        for (int j = 0; j < 4; j++) rowptr[base + j] = sbase[base + j];
    }
    for (int e = blockIdx.x * 256 + t; e < NE; e += gridDim.x * 256) {
        int s = ei[e] & 1023, d = ei[NE + e] & 1023;
        int pos = sbase[d] + atomicAdd(&cursor[d], 1);
        if (pos < NE) ssrc[pos] = s;
    }
}

// ---------------------------------------------------------------------------
// fused_layer: block = one dst node. Chunks of <=64 of its edges through the
// XOR-swizzled LDS h1 tile (verified layout), MFMA vs fragment-ordered W2,
// masked per-thread max + 2x shfl_xor reduce over the q-group, +bias, relu.
// Then (l<4) the next layer's node row [A|B] as a coalesced GEMV over WpT,
// or (l==4) the final relu'd row straight to out. No atomics, no agg buffers.
// ---------------------------------------------------------------------------
template <bool LAST>
__global__ __launch_bounds__(256, 4) void fused_layer(
        const _Float16* __restrict__ node_ab,
        const int* __restrict__ ssrc,
        const int* __restrict__ rowptr,
        const int* __restrict__ counts,
        const _Float16* __restrict__ W2,
        const float* __restrict__ b2,
        const _Float16* __restrict__ WpT,
        const float* __restrict__ bn,
        _Float16* __restrict__ node_out,
        float* __restrict__ out) {
    __shared__ _Float16 h1[64 * 256];
    __shared__ float smax[256];
    int d = blockIdx.x;
    int t = threadIdx.x;
    int wave = t >> 6, lane = t & 63;
    int q = lane >> 4, mn = lane & 15;
    int base = rowptr[d];
    int cnt = counts[d];
    const _Float16* W2w = W2 + wave * 16384;
    const _Float16* arow = node_ab + (size_t)d * 512;

    float tmax[4];
#pragma unroll
    for (int nt = 0; nt < 4; nt++) tmax[nt] = -3.0e38f;

    int srow = t & 63;          // staging: edge row
    int scb = t >> 6;           // staging: 64-half col block 0..3

    for (int c0 = 0; c0 < cnt; c0 += 64) {  // cnt block-uniform -> no divergence
        int lim = cnt - c0;                 // valid rows this chunk (>=1)
        __syncthreads();                    // protect h1 reuse across chunks
        {
            half8 hv[8];
            if (srow < lim) {
                int sn = ssrc[base + c0 + srow];
                const _Float16* pa = arow + scb * 64;
                const _Float16* pb = node_ab + (size_t)sn * 512 + 256 + scb * 64;
#pragma unroll
                for (int i = 0; i < 8; i++) {
                    half8 av = *(const half8*)(pa + i * 8);   // L1-broadcast
                    half8 bv = *(const half8*)(pb + i * 8);
                    half8 h = av + bv;
#pragma unroll
                    for (int j = 0; j < 8; j++) h[j] = h[j] > (_Float16)0 ? h[j] : (_Float16)0;
                    hv[i] = h;
                }
            } else {
                half8 z = {};
#pragma unroll
                for (int i = 0; i < 8; i++) hv[i] = z;        // pad rows -> h=0
            }
#pragma unroll
            for (int i = 0; i < 8; i++) {
                int c = scb * 8 + i;
                int p = (c & ~7) | ((c ^ srow) & 7);          // XOR swizzle
                *(half8*)(&h1[srow * 256 + p * 8]) = hv[i];
            }
        }
        __syncthreads();

        floatx4 acc[4][4] = {};
#pragma unroll
        for (int kk = 0; kk < 8; kk++) {
            half8 bf[4];
#pragma unroll
            for (int nt = 0; nt < 4; nt++)
                bf[nt] = *(const half8*)(W2w + (kk * 4 + nt) * 512 + lane * 8);
            half8 af[4];
#pragma unroll
            for (int mt = 0; mt < 4; mt++) {
                int r = mt * 16 + mn;
                int c = kk * 4 + q;
                int p = (c & ~7) | ((c ^ r) & 7);
                af[mt] = *(const half8*)(&h1[r * 256 + p * 8]);
            }
#pragma unroll
            for (int mt = 0; mt < 4; mt++)
#pragma unroll
                for (int nt = 0; nt < 4; nt++)
                    acc[mt][nt] = __builtin_amdgcn_mfma_f32_16x16x32_f16(af[mt], bf[nt], acc[mt][nt], 0, 0, 0);
        }
        // masked fold into running max (padded rows excluded)
#pragma unroll
        for (int mt = 0; mt < 4; mt++) {
#pragma unroll
            for (int r2 = 0; r2 < 4; r2++) {
                int er = mt * 16 + q * 4 + r2;
                if (er < lim) {
#pragma unroll
                    for (int nt = 0; nt < 4; nt++)
                        tmax[nt] = fmaxf(tmax[nt], acc[mt][nt][r2]);
                }
            }
        }
    }

    // reduce across the 4 q-lanes (lane bits 4,5), add bias, relu.
    // empty bucket: tmax=-3e38 -> relu -> 0, matching segment_max+where+relu.
#pragma unroll
    for (int nt = 0; nt < 4; nt++) {
        float v = tmax[nt];
        v = fmaxf(v, __shfl_xor(v, 16, 64));
        v = fmaxf(v, __shfl_xor(v, 32, 64));
        int col = wave * 64 + nt * 16 + mn;
        float r = v + b2[col];
        r = r > 0.f ? r : 0.f;
        if (q == 0) smax[col] = r;
    }
    __syncthreads();

    if (LAST) {
        out[(size_t)d * HH + t] = smax[t];
        return;
    }

    // GEMV: node_out[d][t] = sum_k h[k]*(Wa-Wb)[t][k] + bn[t]   (A part)
    //       node_out[d][256+t] = sum_k h[k]*Wb[t][k]            (B part)
    // WpT[k][n] layout -> per-k the wave reads 128B contiguous (coalesced).
    float acc_a = bn[t];
    float acc_b = 0.f;
    const _Float16* wt = WpT + t;
#pragma unroll 8
    for (int k = 0; k < 256; k++) {
        float h = smax[k];                       // LDS broadcast
        acc_a = fmaf(h, (float)wt[(size_t)k * 512], acc_a);
        acc_b = fmaf(h, (float)wt[(size_t)k * 512 + 256], acc_b);
    }
    node_out[(size_t)d * 512 + t] = (_Float16)acc_a;
    node_out[(size_t)d * 512 + 256 + t] = (_Float16)acc_b;
}

extern "C" void kernel_launch(void* const* d_in, const int* in_sizes, int n_in,
                              void* d_out, int out_size, void* d_ws, size_t ws_size,
                              hipStream_t stream) {
    const float* x = (const float*)d_in[0];
    const int* ei = (const int*)d_in[1];  // int32 per harness contract
    PrepArgs pa;
    const float* b0s[5];
    const float* b1s[5];
    for (int l = 0; l < 5; l++) {
        pa.w0[l] = (const float*)d_in[2 + 4 * l];
        b0s[l] = (const float*)d_in[3 + 4 * l];
        pa.w1[l] = (const float*)d_in[4 + 4 * l];
        b1s[l] = (const float*)d_in[5 + 4 * l];
    }

    int* ssrc = (int*)d_ws;                              // 64000 ints
    int* counts = ssrc + NE;                             // 1024
    int* cursor = counts + 1024;                         // 1024
    int* rowptr = cursor + 1024;                         // 1024
    _Float16* nab0 = (_Float16*)(rowptr + 1024);         // [1024][512] fp16
    _Float16* nab1 = nab0 + 1024 * 512;                  // [1024][512] fp16
    _Float16* wnode0 = nab1 + 1024 * 512;                // 65536 halfs
    _Float16* w2h = wnode0 + 65536;                      // 5 x 65536 halfs
    _Float16* wpT = w2h + 5 * 65536;                     // 4 x 131072 halfs

    hipLaunchKernelGGL(k_prep2, dim3(256), dim3(256), 0, stream,
                       pa, wnode0, w2h, wpT, counts, cursor);
    hipLaunchKernelGGL(k_hist_node0, dim3(256), dim3(256), 0, stream,
                       ei, counts, x, wnode0, b0s[0], nab0);
    hipLaunchKernelGGL(k_scatter2, dim3(NE / 256), dim3(256), 0, stream,
                       ei, counts, cursor, rowptr, ssrc);

    _Float16* nab[2] = {nab0, nab1};
    for (int l = 0; l < 4; l++) {
        hipLaunchKernelGGL((fused_layer<false>), dim3(NN), dim3(256), 0, stream,
                           nab[l & 1], ssrc, rowptr, counts,
                           w2h + (size_t)l * 65536, b1s[l],
                           wpT + (size_t)l * 131072, b0s[l + 1],
                           nab[(l + 1) & 1], (float*)nullptr);
    }
    hipLaunchKernelGGL((fused_layer<true>), dim3(NN), dim3(256), 0, stream,
                       nab[0], ssrc, rowptr, counts,
                       w2h + (size_t)4 * 65536, b1s[4],
                       (const _Float16*)nullptr, (const float*)nullptr,
                       (_Float16*)nullptr, (float*)d_out);
}

// Round 3
// 279.045 us; speedup vs baseline: 3.9217x; 1.9286x over previous
//
#include <hip/hip_runtime.h>

#define NN 1000
#define NE 64000
#define HH 256

typedef _Float16 half8 __attribute__((ext_vector_type(8)));
typedef float floatx4 __attribute__((ext_vector_type(4)));

struct PrepArgs { const float* w0[5]; const float* w1[5]; };

// ---------------------------------------------------------------------------
// Pipeline (12 dispatches; boundaries measured cheap ~2-3 µs):
//   1. k_prep       : zero counts/cursor/aggA; swizzle all weights to fp16
//                     MFMA fragment order (verified layout from baseline)
//   2. k_hist_node0 : dst histogram (4 blocks) + layer-0 node GEMM (252)
//   3. k_scatter2   : per-block replicated prefix scan + counting-sort scatter
//   4.. 5x edge_gemm2 + 4x k_node_zero
// edge_gemm2 change vs baseline: epilogue routes INTERIOR dst runs (sorted
// edges, run not touching tile row 0/63 => exclusive to this block) to plain
// coalesced stores; only the <=2 boundary runs use device-scope atomicMax.
// Baseline epilogue did ~2048 atomicMax/block = ~2M coherence-point RMWs
// (~250 MB of TCC traffic) per layer -- the measured 2.6 TB/s bottleneck.
// Final layer keeps the baseline fp32 atomic epilogue (bit-identical d_out).
// ---------------------------------------------------------------------------

__global__ __launch_bounds__(256) void k_prep(PrepArgs pa,
                                              _Float16* wnode, _Float16* w2h,
                                              int* counts, int* cursor,
                                              float* aggA) {
    int gtid = blockIdx.x * 256 + threadIdx.x;
    int gstride = gridDim.x * 256;
    for (int i = gtid; i < 1024; i += gstride) { counts[i] = 0; cursor[i] = 0; }
    for (int l = 0; l < 5; l++) {
        const int KK = l ? 8 : 4;
        const int D = KK * 32;
        const int lgKK = l ? 3 : 2;
        const float* w0 = pa.w0[l];
        _Float16* wn = wnode + l * 131072;
        for (int i = gtid; i < 16384 * KK; i += gstride) {
            int j = i & 7;
            int lane = (i >> 3) & 63;
            int nt = (i >> 9) & 1;
            int kk = (i >> 10) & (KK - 1);
            int slice = i >> (10 + lgKK);
            int mn = lane & 15, q = lane >> 4;
            int n = slice * 32 + nt * 16 + mn;
            int k = kk * 32 + q * 8 + j;
            float v = (n < 256) ? (w0[n * 2 * D + k] - w0[n * 2 * D + D + k])
                                : w0[(n - 256) * 2 * D + D + k];
            wn[i] = (_Float16)v;
        }
        const float* w1 = pa.w1[l];
        _Float16* w2 = w2h + l * 65536;
        for (int i = gtid; i < 65536; i += gstride) {
            int j = i & 7;
            int lane = (i >> 3) & 63;
            int nt = (i >> 9) & 3;
            int kk = (i >> 11) & 7;
            int ws = (i >> 14) & 3;
            int mn = lane & 15, q = lane >> 4;
            int row = ws * 64 + nt * 16 + mn;
            int col = kk * 32 + q * 8 + j;
            w2[i] = (_Float16)w1[row * 256 + col];
        }
    }
    floatx4 z = {0.f, 0.f, 0.f, 0.f};
    floatx4* p4 = (floatx4*)aggA;
    for (int i = gtid; i < NN * HH / 4; i += gstride) p4[i] = z;
}

// C = X[M,Kd] @ Wn^T, 16x128 tile per block (252 tiles); Wn in fragment order.
template <int NK>
__device__ __forceinline__ void node_tile(const float* __restrict__ X,
                                          const _Float16* __restrict__ Wn,
                                          const float* __restrict__ b0,
                                          _Float16* __restrict__ out, int bid) {
    const int Kd = NK * 32;
    int t = threadIdx.x;
    int wave = t >> 6, lane = t & 63;
    int q = lane >> 4, mn = lane & 15;
    int m0 = (bid % 63) * 16;
    int n0 = (bid / 63) * 128 + wave * 32;
    int slice = (bid / 63) * 4 + wave;
    int rr = m0 + mn;
    if (rr >= NN) rr = NN - 1;

    half8 afa[NK];
    half8 bfa[NK][2];
#pragma unroll
    for (int kk = 0; kk < NK; kk++) {
        int ka = kk * 32 + q * 8;
        const float* p = X + (size_t)rr * Kd + ka;
        floatx4 x0 = *(const floatx4*)p;
        floatx4 x1 = *(const floatx4*)(p + 4);
        half8 aa;
#pragma unroll
        for (int j = 0; j < 4; j++) { aa[j] = (_Float16)x0[j]; aa[4 + j] = (_Float16)x1[j]; }
        afa[kk] = aa;
        bfa[kk][0] = *(const half8*)(Wn + (((slice * NK + kk) * 2 + 0) * 64 + lane) * 8);
        bfa[kk][1] = *(const half8*)(Wn + (((slice * NK + kk) * 2 + 1) * 64 + lane) * 8);
    }
    floatx4 acc[2] = {};
#pragma unroll
    for (int kk = 0; kk < NK; kk++) {
        acc[0] = __builtin_amdgcn_mfma_f32_16x16x32_f16(afa[kk], bfa[kk][0], acc[0], 0, 0, 0);
        acc[1] = __builtin_amdgcn_mfma_f32_16x16x32_f16(afa[kk], bfa[kk][1], acc[1], 0, 0, 0);
    }
#pragma unroll
    for (int nt = 0; nt < 2; nt++) {
        int col = n0 + nt * 16 + mn;
        float bias = (col < 256) ? b0[col] : 0.f;
#pragma unroll
        for (int r2 = 0; r2 < 4; r2++) {
            int orow = m0 + q * 4 + r2;
            if (orow < NN)
                out[(size_t)orow * 512 + col] = (_Float16)(acc[nt][r2] + bias);
        }
    }
}

// blocks 0..3: dst histogram; blocks 4..255: layer-0 node GEMM
__global__ __launch_bounds__(256) void k_hist_node0(const int* __restrict__ ei,
                                                    int* __restrict__ counts,
                                                    const float* __restrict__ X,
                                                    const _Float16* __restrict__ Wn,
                                                    const float* __restrict__ b0,
                                                    _Float16* __restrict__ out) {
    int bid = blockIdx.x;
    if (bid < 4) {
        for (int e = bid * 256 + threadIdx.x; e < NE; e += 4 * 256)
            atomicAdd(&counts[ei[NE + e] & 1023], 1);
    } else {
        node_tile<4>(X, Wn, b0, out, bid - 4);
    }
}

// Per-block replicated exclusive scan (kills the single-block scan dispatch),
// then counting-sort scatter of (src,dst) by dst.
__global__ __launch_bounds__(256) void k_scatter2(const int* __restrict__ ei,
                                                  const int* __restrict__ counts,
                                                  int* __restrict__ cursor,
                                                  int* __restrict__ ssrc,
                                                  int* __restrict__ sdst) {
    __shared__ int sbase[1024];
    __shared__ int ssum[256];
    int t = threadIdx.x;
    int base = t * 4;
    int c4[4]; int sum = 0;
#pragma unroll
    for (int j = 0; j < 4; j++) { c4[j] = counts[base + j]; sum += c4[j]; }
    ssum[t] = sum;
    __syncthreads();
    for (int d = 1; d < 256; d <<= 1) {
        int v = (t >= d) ? ssum[t - d] : 0;
        __syncthreads();
        ssum[t] += v;
        __syncthreads();
    }
    int run = (t > 0) ? ssum[t - 1] : 0;
#pragma unroll
    for (int j = 0; j < 4; j++) { sbase[base + j] = run; run += c4[j]; }
    __syncthreads();
    for (int e = blockIdx.x * 256 + t; e < NE; e += gridDim.x * 256) {
        int s = ei[e] & 1023, d = ei[NE + e] & 1023;
        int pos = sbase[d] + atomicAdd(&cursor[d], 1);
        if (pos < NE) { ssrc[pos] = s; sdst[pos] = d; }
    }
}

// blocks 0..251: node GEMM layer l+1 (reads agg_in); blocks 252..315: zero agg_next
__global__ __launch_bounds__(256) void k_node_zero(const float* __restrict__ agg_in,
                                                   const _Float16* __restrict__ Wn,
                                                   const float* __restrict__ b0,
                                                   _Float16* __restrict__ out,
                                                   float* __restrict__ agg_next) {
    int bid = blockIdx.x;
    if (bid < 252) {
        node_tile<8>(agg_in, Wn, b0, out, bid);
    } else {
        floatx4 z = {0.f, 0.f, 0.f, 0.f};
        floatx4* p4 = (floatx4*)agg_next;
        for (int i = (bid - 252) * 256 + (int)threadIdx.x; i < NN * HH / 4; i += 64 * 256)
            p4[i] = z;
    }
}

// 64 sorted edges x 256 cols. h1 = relu(a[dst]+b[src]) in XOR-swizzled LDS;
// W2 in fragment order -> coalesced b128 loads.
// Epilogue (LAST=false): h2=relu(acc+bias) -> LDS (same swizzle, fp16 --
// rounding commutes with max and next GEMM casts to fp16 anyway), then each
// thread owns one column and scans the 64 sorted rows: interior runs get a
// plain coalesced store (block-exclusive), boundary runs atomicMax.
// Epilogue (LAST=true): baseline per-lane merged-run fp32 atomicMax (keeps
// d_out numerics bit-identical to the verified baseline).
template <bool LAST>
__global__ __launch_bounds__(256, 4) void edge_gemm2(const _Float16* __restrict__ node_ab,
                          const int* __restrict__ ssrc, const int* __restrict__ sdst,
                          const _Float16* __restrict__ W2, const float* __restrict__ b2,
                          float* __restrict__ agg) {
    __shared__ _Float16 h1[64 * 256];
    __shared__ int sd[64];
    int t = threadIdx.x;
    int e0 = blockIdx.x * 64;
    int wave = t >> 6, lane = t & 63;
    int q = lane >> 4, mn = lane & 15;
    int n0 = wave * 64;
    const _Float16* W2w = W2 + wave * 16384;  // this wave's fragment slice

    if (t < 64) sd[t] = sdst[e0 + t];
    {   // staging: all 16 gather loads in flight
        int row = t & 63;
        int cb = (t >> 6) * 8;
        int dn = sdst[e0 + row], sn = ssrc[e0 + row];
        const _Float16* pa = node_ab + (size_t)dn * 512 + cb * 8;
        const _Float16* pb = node_ab + (size_t)sn * 512 + 256 + cb * 8;
        half8 av[8], bv[8];
#pragma unroll
        for (int i = 0; i < 8; i++) av[i] = *(const half8*)(pa + i * 8);
#pragma unroll
        for (int i = 0; i < 8; i++) bv[i] = *(const half8*)(pb + i * 8);
#pragma unroll
        for (int i = 0; i < 8; i++) {
            int c = cb + i;
            int p = (c & ~7) | ((c ^ row) & 7);
            half8 hv = av[i] + bv[i];
#pragma unroll
            for (int j = 0; j < 8; j++) hv[j] = hv[j] > (_Float16)0 ? hv[j] : (_Float16)0;
            *(half8*)(&h1[row * 256 + p * 8]) = hv;
        }
    }
    __syncthreads();

    floatx4 acc[4][4] = {};
#pragma unroll
    for (int kk = 0; kk < 8; kk++) {
        half8 bf[4];
#pragma unroll
        for (int nt = 0; nt < 4; nt++)
            bf[nt] = *(const half8*)(W2w + (kk * 4 + nt) * 512 + lane * 8);  // coalesced
        half8 af[4];
#pragma unroll
        for (int mt = 0; mt < 4; mt++) {
            int r = mt * 16 + mn;
            int c = kk * 4 + q;
            int p = (c & ~7) | ((c ^ r) & 7);
            af[mt] = *(const half8*)(&h1[r * 256 + p * 8]);
        }
#pragma unroll
        for (int mt = 0; mt < 4; mt++)
#pragma unroll
            for (int nt = 0; nt < 4; nt++)
                acc[mt][nt] = __builtin_amdgcn_mfma_f32_16x16x32_f16(af[mt], bf[nt], acc[mt][nt], 0, 0, 0);
    }

    if (LAST) {
        // baseline epilogue: per-lane merged-run atomicMax (fp32 exact)
#pragma unroll
        for (int nt = 0; nt < 4; nt++) {
            int col = n0 + nt * 16 + mn;
            float bias = b2[col];
            int curd = -1;
            float curv = 0.f;
#pragma unroll
            for (int mt = 0; mt < 4; mt++) {
#pragma unroll
                for (int r2 = 0; r2 < 4; r2++) {
                    int er = mt * 16 + q * 4 + r2;  // monotone -> sorted runs merge
                    int d = sd[er];
                    float v = acc[mt][nt][r2] + bias;
                    v = v > 0.f ? v : 0.f;
                    if (d != curd) {
                        if (curd >= 0 && curv > 0.f)
                            atomicMax((unsigned int*)(agg + (size_t)curd * HH + col), __float_as_uint(curv));
                        curd = d;
                        curv = v;
                    } else {
                        curv = fmaxf(curv, v);
                    }
                }
            }
            if (curd >= 0 && curv > 0.f)
                atomicMax((unsigned int*)(agg + (size_t)curd * HH + col), __float_as_uint(curv));
        }
        return;
    }

    __syncthreads();  // all h1 fragment reads done before overwrite
    // h2 = relu(acc + bias) -> back into h1 (fp16), same XOR swizzle at
    // 8-half-group granularity: addr(r,c) = r*256 + pg(c>>3, r)*8 + (c&7)
#pragma unroll
    for (int nt = 0; nt < 4; nt++) {
        int col = n0 + nt * 16 + mn;
        float bias = b2[col];
        int g = col >> 3, o = col & 7;
#pragma unroll
        for (int mt = 0; mt < 4; mt++) {
#pragma unroll
            for (int r2 = 0; r2 < 4; r2++) {
                int row = mt * 16 + q * 4 + r2;
                float v = acc[mt][nt][r2] + bias;
                v = v > 0.f ? v : 0.f;
                int pg = (g & ~7) | ((g ^ row) & 7);
                h1[row * 256 + pg * 8 + o] = (_Float16)v;
            }
        }
    }
    __syncthreads();

    // column-owner run scan: thread t owns column t. Control flow is uniform
    // (all threads read the same sd[] sequence). Interior run => this block
    // holds ALL edges of that dst => plain store; runs touching row 0/63 may
    // continue in the neighbor block => atomicMax. agg is zero-initialized.
    {
        int c = t;
        int g = c >> 3, o = c & 7;
        float* aggc = agg + c;
        float m = (float)h1[g * 8 + o];  // row 0: pg = g
        bool sedge = true;               // current run touches tile start
        int prevd = sd[0];
#pragma unroll 8
        for (int r = 1; r < 64; r++) {
            int d = sd[r];
            int pg = (g & ~7) | ((g ^ r) & 7);
            float v = (float)h1[r * 256 + pg * 8 + o];
            if (d != prevd) {            // run ended at r-1 (interior end)
                if (sedge) {
                    if (m > 0.f)
                        atomicMax((unsigned int*)(aggc + (size_t)prevd * HH), __float_as_uint(m));
                } else {
                    if (m > 0.f)
                        aggc[(size_t)prevd * HH] = m;   // block-exclusive
                }
                m = v; sedge = false; prevd = d;
            } else {
                m = fmaxf(m, v);
            }
        }
        // final run touches tile end -> may continue in next block
        if (m > 0.f)
            atomicMax((unsigned int*)(aggc + (size_t)prevd * HH), __float_as_uint(m));
    }
}

extern "C" void kernel_launch(void* const* d_in, const int* in_sizes, int n_in,
                              void* d_out, int out_size, void* d_ws, size_t ws_size,
                              hipStream_t stream) {
    const float* x = (const float*)d_in[0];
    const int* ei = (const int*)d_in[1];  // int32 per harness contract
    PrepArgs pa;
    const float* b0s[5];
    const float* b1s[5];
    for (int l = 0; l < 5; l++) {
        pa.w0[l] = (const float*)d_in[2 + 4 * l];
        b0s[l] = (const float*)d_in[3 + 4 * l];
        pa.w1[l] = (const float*)d_in[4 + 4 * l];
        b1s[l] = (const float*)d_in[5 + 4 * l];
    }

    int* ssrc = (int*)d_ws;                              // 256 KB
    int* sdst = ssrc + NE;                               // 256 KB
    int* counts = sdst + NE;                             // 4 KB
    int* cursor = counts + 1024;                         // 4 KB
    _Float16* node_ab = (_Float16*)(cursor + 1024);      // [1024][512] fp16, 1 MB
    float* aggA = (float*)(node_ab + 1024 * 512);        // 1 MB
    float* aggB = aggA + NN * HH;                        // 1 MB
    _Float16* wnode = (_Float16*)(aggB + NN * HH);       // 5 x 131072 halfs
    _Float16* w2h = wnode + 5 * 131072;                  // 5 x 65536 halfs

    hipLaunchKernelGGL(k_prep, dim3(256), dim3(256), 0, stream,
                       pa, wnode, w2h, counts, cursor, aggA);
    hipLaunchKernelGGL(k_hist_node0, dim3(256), dim3(256), 0, stream,
                       ei, counts, x, wnode, b0s[0], node_ab);
    hipLaunchKernelGGL(k_scatter2, dim3(NE / 256), dim3(256), 0, stream,
                       ei, counts, cursor, ssrc, sdst);

    float* aggs[5] = {aggA, aggB, aggA, aggB, (float*)d_out};
    for (int l = 0; l < 4; l++) {
        hipLaunchKernelGGL((edge_gemm2<false>), dim3(NE / 64), dim3(256), 0, stream,
                           node_ab, ssrc, sdst, w2h + (size_t)l * 65536, b1s[l], aggs[l]);
        hipLaunchKernelGGL(k_node_zero, dim3(252 + 64), dim3(256), 0, stream,
                           aggs[l], wnode + (size_t)(l + 1) * 131072, b0s[l + 1],
                           node_ab, aggs[l + 1]);
    }
    hipLaunchKernelGGL((edge_gemm2<true>), dim3(NE / 64), dim3(256), 0, stream,
                       node_ab, ssrc, sdst, w2h + (size_t)4 * 65536, b1s[4], (float*)d_out);
}